// Round 2
// 574.581 us; speedup vs baseline: 1.0066x; 1.0066x over previous
//
#include <hip/hip_runtime.h>
#include <hip/hip_bf16.h>

// MultiHeadSelfAttention: B=4, S=1024, D=512(d_model = per-head dim), H=8
// out  = [B*S, D]    fp32 at d_out
// attn = [H*B, S, S] fp32 at d_out + B*S*D
//
// All GEMMs are BT (B given as [N][K] bf16, k-contiguous).
// V is computed directly transposed (vT[hb][d][s]) via a row-bias GEMM.
//
// Step-5 (ctx = attn @ vT^T): A (fp32 attn) staged raw-fp32 into LDS via
// async global_load_lds (XOR-swizzled source chunks to kill the 16-way bank
// conflict on the fp32 fragment reads), converted to bf16 at fragment-load
// time with v_cvt_pk_bf16_f32 (idle VALU slot in the compute phase).
//
// d_ws layout (87.1 MB <= 100.7 MB proven available):
//   xb   bf16 [4096,512]    4 MB
//   WqT  bf16 [4096,512]    4 MB
//   WkT  bf16 [4096,512]    4 MB
//   WvT  bf16 [4096,512]    4 MB
//   WoT  bf16 [512,4096]    4 MB
//   buf1 bf16 [4096,4096]  33.5 MB   (q  -> vT)
//   buf2 bf16 [4096,4096]  33.5 MB   (k  -> ctx)

typedef unsigned short u16;
typedef __attribute__((ext_vector_type(8))) short short8;
typedef __attribute__((ext_vector_type(4))) float f32x4;
typedef __attribute__((ext_vector_type(2))) unsigned int u32x2;

#define BK 32

__device__ __forceinline__ u16 f2bf(float f) {
    union { float f; unsigned u; } v; v.f = f;
    unsigned u = v.u;
    u += 0x7fffu + ((u >> 16) & 1u);   // round-to-nearest-even
    return (u16)(u >> 16);
}

__device__ __forceinline__ void gl2lds16(const void* g, void* l) {
    __builtin_amdgcn_global_load_lds(
        (const __attribute__((address_space(1))) void*)g,
        (__attribute__((address_space(3))) void*)l, 16, 0, 0);
}

// C = scale * (A @ B^T) + bias.  A:[M,K] (fp32 or bf16), B:[N,K] bf16.
// Tile: BM=MF*32 x BN=NF*32, 4 waves in 2x2, BK=32, 16x16x32 bf16 MFMA.
// Batch via blockIdx.z: zh = z/nb, zb = z%nb.
// AF32: A tile staged as raw fp32 in LDS (gl2lds16, source-chunk XOR swizzle),
//       converted to bf16 during fragment load (cvt_pk, compute phase).
template<int MF, int NF, bool AF32, bool OUTF32, bool ROWBIAS>
__global__ __launch_bounds__(256)
void gemm_bt(const void* __restrict__ Ap, int lda, long long sAh, long long sAb,
             const u16* __restrict__ Bp, int ldb, long long sBh, long long sBb,
             void* __restrict__ Cp, int ldc, long long sCh, long long sCb,
             int K, const float* __restrict__ bias, long long sbias,
             float scale, int nb)
{
    constexpr int BMt = MF * 32, BNt = NF * 32;
    // AF32: rows are 32 f32 = 64 u16 = 128 B (8 x 16B chunks, XOR-swizzled)
    __shared__ __attribute__((aligned(16))) u16 Alds[BMt][AF32 ? 2 * BK : BK];
    __shared__ __attribute__((aligned(16))) u16 Blds[BNt][BK];   // [n][k]

    const int z  = blockIdx.z;
    const int zh = z / nb, zb = z % nb;

    const int m0 = blockIdx.y * BMt;
    const int n0 = blockIdx.x * BNt;

    const int tid  = threadIdx.x;
    const int lane = tid & 63;
    const int wave = tid >> 6;
    const int wm = (wave >> 1) * (MF * 16);
    const int wn = (wave & 1) * (NF * 16);

    const float* Afp = (const float*)Ap + (long long)zh * sAh + (long long)zb * sAb;
    const u16*   Abf = (const u16*)Ap + (long long)zh * sAh + (long long)zb * sAb;
    const u16*   Bbf = Bp + (long long)zh * sBh + (long long)zb * sBb;

    f32x4 acc[MF][NF] = {};

    for (int kt = 0; kt < K; kt += BK) {
        __syncthreads();
        // ---- stage A tile ----
        if (AF32) {
            // raw fp32 via async global_load_lds; LDS dest linear, global
            // source chunk XOR-swizzled: chunk c of row r holds global
            // k-chunk (c ^ (r&7)).  (both-sides swizzle, involution)
            #pragma unroll
            for (int i = 0; i < BMt / 32; ++i) {
                int idx = i * 256 + tid;      // 16B-chunk index, linear in LDS
                int row = idx >> 3;
                int c   = idx & 7;
                int cs  = c ^ (row & 7);
                gl2lds16(Afp + (long long)(m0 + row) * lda + kt + (cs << 2),
                         (u16*)Alds + idx * 8);
            }
        } else {
            #pragma unroll
            for (int i = 0; i < BMt / 64; ++i) {
                int idx = i * 256 + tid;
                int row = idx >> 2;
                int kq  = (idx & 3) << 3;
                gl2lds16(Abf + (long long)(m0 + row) * lda + (kt + kq), &Alds[row][kq]);
            }
        }
        // ---- stage B tile -> Blds[n][k] ----
        #pragma unroll
        for (int i = 0; i < BNt / 64; ++i) {
            int idx = i * 256 + tid;
            int row = idx >> 2;
            int kq  = (idx & 3) << 3;
            gl2lds16(Bbf + (long long)(n0 + row) * ldb + (kt + kq), &Blds[row][kq]);
        }
        __syncthreads();

        // ---- compute: MF x NF tiles of 16x16x32 MFMA ----
        const int kq = (lane >> 4) << 3;
        const int fr = lane & 15;
        short8 af[MF], bfr[NF];
        if (AF32) {
            const int c0 = (lane >> 4) << 1;   // first 16B chunk (4 f32) of my k-slice
            #pragma unroll
            for (int im = 0; im < MF; ++im) {
                int row = wm + im * 16 + fr;
                int s   = row & 7;
                const float* ar = (const float*)&Alds[row][0];
                f32x4 lo = *(const f32x4*)(ar + (((c0    ) ^ s) << 2));
                f32x4 hi = *(const f32x4*)(ar + (((c0 + 1) ^ s) << 2));
                union { short8 v; __hip_bfloat162 h[4]; } a;
                a.h[0] = __float22bfloat162_rn(make_float2(lo.x, lo.y));
                a.h[1] = __float22bfloat162_rn(make_float2(lo.z, lo.w));
                a.h[2] = __float22bfloat162_rn(make_float2(hi.x, hi.y));
                a.h[3] = __float22bfloat162_rn(make_float2(hi.z, hi.w));
                af[im] = a.v;
            }
        } else {
            #pragma unroll
            for (int im = 0; im < MF; ++im)
                af[im] = *(const short8*)(&Alds[wm + im * 16 + fr][kq]);
        }
        #pragma unroll
        for (int in = 0; in < NF; ++in)
            bfr[in] = *(const short8*)(&Blds[wn + in * 16 + fr][kq]);
        #pragma unroll
        for (int im = 0; im < MF; ++im)
            #pragma unroll
            for (int in = 0; in < NF; ++in)
                acc[im][in] = __builtin_amdgcn_mfma_f32_16x16x32_bf16(
                    af[im], bfr[in], acc[im][in], 0, 0, 0);
    }

    // ---- epilogue: C[row=(lane>>4)*4+r][col=lane&15] ----
    float* Cfp = (float*)Cp + (long long)zh * sCh + (long long)zb * sCb;
    u16*   Cbf = (u16*)Cp + (long long)zh * sCh + (long long)zb * sCb;
    const float* biasp = bias ? bias + (long long)zh * sbias : nullptr;
    const int rb  = (lane >> 4) << 2;
    const int col = lane & 15;
    #pragma unroll
    for (int im = 0; im < MF; ++im) {
        #pragma unroll
        for (int r = 0; r < 4; ++r) {
            int row = m0 + wm + im * 16 + rb + r;
            float rbias = (biasp && ROWBIAS) ? biasp[row] : 0.0f;
            #pragma unroll
            for (int in = 0; in < NF; ++in) {
                int cc = n0 + wn + in * 16 + col;
                float v = acc[im][in][r] * scale;
                if (biasp) v += ROWBIAS ? rbias : biasp[cc];
                if (OUTF32) Cfp[(long long)row * ldc + cc] = v;
                else        Cbf[(long long)row * ldc + cc] = f2bf(v);
            }
        }
    }
}

// In-place softmax over rows of 1024 fp32. One 256-thread block per row.
__global__ __launch_bounds__(256)
void softmax_kernel(float* __restrict__ attn)
{
    const long long row = blockIdx.x;
    float* p = attn + row * 1024;
    const int tid  = threadIdx.x;
    const int lane = tid & 63;
    const int wave = tid >> 6;
    __shared__ float red[8];

    f32x4 v = *(f32x4*)(p + tid * 4);
    float mx = fmaxf(fmaxf(v.x, v.y), fmaxf(v.z, v.w));
    #pragma unroll
    for (int off = 1; off < 64; off <<= 1)
        mx = fmaxf(mx, __shfl_xor(mx, off, 64));
    if (lane == 0) red[wave] = mx;
    __syncthreads();
    mx = fmaxf(fmaxf(red[0], red[1]), fmaxf(red[2], red[3]));

    v.x = __expf(v.x - mx);
    v.y = __expf(v.y - mx);
    v.z = __expf(v.z - mx);
    v.w = __expf(v.w - mx);
    float s = v.x + v.y + v.z + v.w;
    #pragma unroll
    for (int off = 1; off < 64; off <<= 1)
        s += __shfl_xor(s, off, 64);
    if (lane == 0) red[4 + wave] = s;
    __syncthreads();
    s = red[4] + red[5] + red[6] + red[7];
    float inv = 1.0f / s;
    v.x *= inv; v.y *= inv; v.z *= inv; v.w *= inv;
    *(f32x4*)(p + tid * 4) = v;
}

// x fp32 -> bf16 elementwise
__global__ __launch_bounds__(256)
void cvt_kernel(const float* __restrict__ in, u16* __restrict__ out)
{
    long long i = (long long)blockIdx.x * 256 + threadIdx.x;
    f32x4 v = *(const f32x4*)(in + i * 4);
    u32x2 p;
    p.x = (unsigned)f2bf(v.x) | ((unsigned)f2bf(v.y) << 16);
    p.y = (unsigned)f2bf(v.z) | ((unsigned)f2bf(v.w) << 16);
    *(u32x2*)(out + i * 4) = p;
}

// transpose fp32 [R][C] -> bf16 [C][R]; 64x64 tiles, grid (C/64, R/64)
__global__ __launch_bounds__(256)
void wtrans_kernel(const float* __restrict__ in, u16* __restrict__ out, int R, int C)
{
    __shared__ __attribute__((aligned(16))) u16 t[64][72];
    const int r0 = blockIdx.y * 64, c0 = blockIdx.x * 64;
    const int tid = threadIdx.x;
    const int lr = tid >> 4;
    const int lc = (tid & 15) << 2;
    #pragma unroll
    for (int j = 0; j < 4; ++j) {
        int rr = lr + j * 16;
        f32x4 v = *(const f32x4*)(in + (long long)(r0 + rr) * C + c0 + lc);
        u32x2 p;
        p.x = (unsigned)f2bf(v.x) | ((unsigned)f2bf(v.y) << 16);
        p.y = (unsigned)f2bf(v.z) | ((unsigned)f2bf(v.w) << 16);
        *(u32x2*)(&t[rr][lc]) = p;
    }
    __syncthreads();
    const int oc = tid >> 2;
    const int rs = (tid & 3) << 4;
    union { short8 v; u16 e[8]; } a, b;
    #pragma unroll
    for (int j = 0; j < 8; ++j) a.e[j] = t[rs + j][oc];
    #pragma unroll
    for (int j = 0; j < 8; ++j) b.e[j] = t[rs + 8 + j][oc];
    u16* o = out + (long long)(c0 + oc) * R + r0 + rs;
    *(short8*)o = a.v;
    *(short8*)(o + 8) = b.v;
}

extern "C" void kernel_launch(void* const* d_in, const int* in_sizes, int n_in,
                              void* d_out, int out_size, void* d_ws, size_t ws_size,
                              hipStream_t stream)
{
    const float* x  = (const float*)d_in[0];
    const float* Wq = (const float*)d_in[1];
    const float* bq = (const float*)d_in[2];
    const float* Wk = (const float*)d_in[3];
    const float* bk = (const float*)d_in[4];
    const float* Wv = (const float*)d_in[5];
    const float* bv = (const float*)d_in[6];
    const float* Wo = (const float*)d_in[7];
    const float* bo = (const float*)d_in[8];

    const int B = 4, S = 1024, D = 512, H = 8;
    const int HD = H * D;   // 4096
    const int BS = B * S;   // 4096

    float* out  = (float*)d_out;                     // [4096, 512]
    float* attn = out + (long long)BS * D;           // [32, 1024, 1024]

    u16* xb   = (u16*)d_ws;                          // [4096,512]
    u16* WqT  = xb  + (long long)BS * D;
    u16* WkT  = WqT + (long long)HD * D;
    u16* WvT  = WkT + (long long)HD * D;
    u16* WoT  = WvT + (long long)HD * D;             // [512,4096]
    u16* buf1 = WoT + (long long)D * HD;             // [4096,4096]
    u16* buf2 = buf1 + (long long)BS * HD;

    dim3 blk(256);

    // 0) prep: x -> bf16, weights -> transposed bf16
    cvt_kernel<<<dim3(BS * D / 1024), blk, 0, stream>>>(x, xb);
    wtrans_kernel<<<dim3(HD / 64, D / 64), blk, 0, stream>>>(Wq, WqT, D, HD);
    wtrans_kernel<<<dim3(HD / 64, D / 64), blk, 0, stream>>>(Wk, WkT, D, HD);
    wtrans_kernel<<<dim3(HD / 64, D / 64), blk, 0, stream>>>(Wv, WvT, D, HD);
    wtrans_kernel<<<dim3(D / 64, HD / 64), blk, 0, stream>>>(Wo, WoT, HD, D);

    // 1) q = xb @ WqT^T -> buf1 ; k = xb @ WkT^T -> buf2   [128x128 tiles]
    {
        dim3 g(HD / 128, BS / 128, 1);
        gemm_bt<4,4,false,false,false><<<g, blk, 0, stream>>>(
            xb, D, 0, 0, WqT, D, 0, 0, buf1, HD, 0, 0, D, bq, 0, 1.0f, 1);
        gemm_bt<4,4,false,false,false><<<g, blk, 0, stream>>>(
            xb, D, 0, 0, WkT, D, 0, 0, buf2, HD, 0, 0, D, bk, 0, 1.0f, 1);
    }
    // 2) scores = q @ k^T / 512 per (h,b) -> fp32 attn region
    {
        dim3 g(S / 128, S / 128, H * B);
        gemm_bt<4,4,false,true,false><<<g, blk, 0, stream>>>(
            buf1, HD, D, (long long)S * HD,
            buf2, HD, D, (long long)S * HD,
            attn, S, (long long)B * S * S, (long long)S * S,
            D, nullptr, 0, 1.0f / (float)D, B);
    }
    // 3) row softmax in place
    softmax_kernel<<<dim3(H * B * S), blk, 0, stream>>>(attn);
    // 4) vT[hb][d][s] = Wv^T slice @ xb^T + bv  -> buf1 (q dead); row bias
    {
        dim3 g(S / 128, D / 128, H * B);
        gemm_bt<4,4,false,false,true><<<g, blk, 0, stream>>>(
            WvT, D, (long long)D * D, 0,
            xb, D, 0, (long long)S * D,
            buf1, S, (long long)B * D * S, (long long)D * S,
            D, bv, D, 1.0f, B);
    }
    // 5) ctx = attn @ vT^T per (h,b) -> buf2 bf16 (k dead)   [128x256 tiles]
    //    A staged raw-fp32 via gl2lds16 + XOR-swizzle, cvt_pk at frag load.
    {
        dim3 g(D / 256, S / 128, H * B);
        gemm_bt<4,8,true,false,false><<<g, blk, 0, stream>>>(
            attn, S, (long long)B * S * S, (long long)S * S,
            buf1, S, (long long)B * D * S, (long long)D * S,
            buf2, HD, D, (long long)S * HD,
            S, nullptr, 0, 1.0f, B);
    }
    // 6) out = ctx @ WoT^T + bo -> fp32   [64x128 tiles, 256 blocks]
    {
        dim3 g(D / 128, BS / 64, 1);
        gemm_bt<2,4,false,true,false><<<g, blk, 0, stream>>>(
            buf2, HD, 0, 0, WoT, HD, 0, 0, out, D, 0, 0, HD, bo, 0, 1.0f, 1);
    }
}

// Round 3
// 549.573 us; speedup vs baseline: 1.0524x; 1.0455x over previous
//
#include <hip/hip_runtime.h>
#include <hip/hip_bf16.h>

// MultiHeadSelfAttention: B=4, S=1024, D=512(d_model = per-head dim), H=8
// out  = [B*S, D]    fp32 at d_out
// attn = [H*B, S, S] fp32 at d_out + B*S*D
//
// All GEMMs are BT (B given as [N][K] bf16, k-contiguous).
// V is computed directly transposed (vT[hb][d][s]) via a row-bias GEMM.
//
// This round: gemm_bt is double-buffered (one barrier per K-step; next tile's
// global_load_lds issued right after the barrier so HBM latency hides under
// the MFMA phase instead of being drained immediately by vmcnt(0)+s_barrier).
//
// d_ws layout (87.1 MB <= 100.7 MB proven available):
//   xb   bf16 [4096,512]    4 MB
//   WqT  bf16 [4096,512]    4 MB
//   WkT  bf16 [4096,512]    4 MB
//   WvT  bf16 [4096,512]    4 MB
//   WoT  bf16 [512,4096]    4 MB
//   buf1 bf16 [4096,4096]  33.5 MB   (q  -> vT)
//   buf2 bf16 [4096,4096]  33.5 MB   (k  -> ctx)

typedef unsigned short u16;
typedef __attribute__((ext_vector_type(8))) short short8;
typedef __attribute__((ext_vector_type(4))) float f32x4;
typedef __attribute__((ext_vector_type(2))) unsigned int u32x2;

#define BK 32

__device__ __forceinline__ u16 f2bf(float f) {
    union { float f; unsigned u; } v; v.f = f;
    unsigned u = v.u;
    u += 0x7fffu + ((u >> 16) & 1u);   // round-to-nearest-even
    return (u16)(u >> 16);
}

__device__ __forceinline__ void gl2lds16(const void* g, void* l) {
    __builtin_amdgcn_global_load_lds(
        (const __attribute__((address_space(1))) void*)g,
        (__attribute__((address_space(3))) void*)l, 16, 0, 0);
}

// C = scale * (A @ B^T) + bias.  A:[M,K] (fp32 or bf16), B:[N,K] bf16.
// Tile: BM=MF*32 x BN=NF*32, 4 waves in 2x2, BK=32, 16x16x32 bf16 MFMA.
// Batch via blockIdx.z: zh = z/nb, zb = z%nb.
// AF32: A tile staged as raw fp32 in LDS (gl2lds16, source-chunk XOR swizzle),
//       converted to bf16 during fragment load (cvt_pk, compute phase).
// Double-buffered: stage(t+1) issued after the barrier that made tile t
// resident; its latency hides under tile t's ds_read+MFMA phase.
template<int MF, int NF, bool AF32, bool OUTF32, bool ROWBIAS>
__global__ __launch_bounds__(256)
void gemm_bt(const void* __restrict__ Ap, int lda, long long sAh, long long sAb,
             const u16* __restrict__ Bp, int ldb, long long sBh, long long sBb,
             void* __restrict__ Cp, int ldc, long long sCh, long long sCb,
             int K, const float* __restrict__ bias, long long sbias,
             float scale, int nb)
{
    constexpr int BMt = MF * 32, BNt = NF * 32;
    constexpr int AW = AF32 ? 2 * BK : BK;   // A row width in u16
    // AF32: rows are 32 f32 = 64 u16 = 128 B (8 x 16B chunks, XOR-swizzled)
    __shared__ __attribute__((aligned(16))) u16 Alds[2][BMt][AW];
    __shared__ __attribute__((aligned(16))) u16 Blds[2][BNt][BK];

    const int z  = blockIdx.z;
    const int zh = z / nb, zb = z % nb;

    const int m0 = blockIdx.y * BMt;
    const int n0 = blockIdx.x * BNt;

    const int tid  = threadIdx.x;
    const int lane = tid & 63;
    const int wave = tid >> 6;
    const int wm = (wave >> 1) * (MF * 16);
    const int wn = (wave & 1) * (NF * 16);

    const float* Afp = (const float*)Ap + (long long)zh * sAh + (long long)zb * sAb;
    const u16*   Abf = (const u16*)Ap + (long long)zh * sAh + (long long)zb * sAb;
    const u16*   Bbf = Bp + (long long)zh * sBh + (long long)zb * sBb;

    f32x4 acc[MF][NF] = {};

    auto stage = [&](int buf, int kt) {
        // ---- stage A tile ----
        if (AF32) {
            // raw fp32 via async global_load_lds; LDS dest linear, global
            // source chunk XOR-swizzled: chunk c of row r holds global
            // k-chunk (c ^ (r&7)).  (both-sides swizzle, involution)
            #pragma unroll
            for (int i = 0; i < BMt / 32; ++i) {
                int idx = i * 256 + tid;      // 16B-chunk index, linear in LDS
                int row = idx >> 3;
                int c   = idx & 7;
                int cs  = c ^ (row & 7);
                gl2lds16(Afp + (long long)(m0 + row) * lda + kt + (cs << 2),
                         (u16*)&Alds[buf][0][0] + idx * 8);
            }
        } else {
            #pragma unroll
            for (int i = 0; i < BMt / 64; ++i) {
                int idx = i * 256 + tid;
                int row = idx >> 2;
                int kq  = (idx & 3) << 3;
                gl2lds16(Abf + (long long)(m0 + row) * lda + (kt + kq),
                         &Alds[buf][row][kq]);
            }
        }
        // ---- stage B tile -> Blds[n][k] ----
        #pragma unroll
        for (int i = 0; i < BNt / 64; ++i) {
            int idx = i * 256 + tid;
            int row = idx >> 2;
            int kq  = (idx & 3) << 3;
            gl2lds16(Bbf + (long long)(n0 + row) * ldb + (kt + kq),
                     &Blds[buf][row][kq]);
        }
    };

    const int nt = K / BK;
    stage(0, 0);                          // prologue prefetch

    for (int t = 0; t < nt; ++t) {
        const int cur = t & 1;
        __syncthreads();                  // vmcnt(0)+barrier: tile t resident
        if (t + 1 < nt)
            stage(cur ^ 1, (t + 1) * BK); // in flight across the MFMA phase

        // ---- compute: MF x NF tiles of 16x16x32 MFMA ----
        const int kq = (lane >> 4) << 3;
        const int fr = lane & 15;
        short8 af[MF], bfr[NF];
        if (AF32) {
            const int c0 = (lane >> 4) << 1;   // first 16B chunk of my k-slice
            #pragma unroll
            for (int im = 0; im < MF; ++im) {
                int row = wm + im * 16 + fr;
                int s   = row & 7;
                const float* ar = (const float*)&Alds[cur][row][0];
                f32x4 lo = *(const f32x4*)(ar + (((c0    ) ^ s) << 2));
                f32x4 hi = *(const f32x4*)(ar + (((c0 + 1) ^ s) << 2));
                union { short8 v; __hip_bfloat162 h[4]; } a;
                a.h[0] = __float22bfloat162_rn(make_float2(lo.x, lo.y));
                a.h[1] = __float22bfloat162_rn(make_float2(lo.z, lo.w));
                a.h[2] = __float22bfloat162_rn(make_float2(hi.x, hi.y));
                a.h[3] = __float22bfloat162_rn(make_float2(hi.z, hi.w));
                af[im] = a.v;
            }
        } else {
            #pragma unroll
            for (int im = 0; im < MF; ++im)
                af[im] = *(const short8*)(&Alds[cur][wm + im * 16 + fr][kq]);
        }
        #pragma unroll
        for (int in = 0; in < NF; ++in)
            bfr[in] = *(const short8*)(&Blds[cur][wn + in * 16 + fr][kq]);
        #pragma unroll
        for (int im = 0; im < MF; ++im)
            #pragma unroll
            for (int in = 0; in < NF; ++in)
                acc[im][in] = __builtin_amdgcn_mfma_f32_16x16x32_bf16(
                    af[im], bfr[in], acc[im][in], 0, 0, 0);
    }

    // ---- epilogue: C[row=(lane>>4)*4+r][col=lane&15] ----
    float* Cfp = (float*)Cp + (long long)zh * sCh + (long long)zb * sCb;
    u16*   Cbf = (u16*)Cp + (long long)zh * sCh + (long long)zb * sCb;
    const float* biasp = bias ? bias + (long long)zh * sbias : nullptr;
    const int rb  = (lane >> 4) << 2;
    const int col = lane & 15;
    #pragma unroll
    for (int im = 0; im < MF; ++im) {
        #pragma unroll
        for (int r = 0; r < 4; ++r) {
            int row = m0 + wm + im * 16 + rb + r;
            float rbias = (biasp && ROWBIAS) ? biasp[row] : 0.0f;
            #pragma unroll
            for (int in = 0; in < NF; ++in) {
                int cc = n0 + wn + in * 16 + col;
                float v = acc[im][in][r] * scale;
                if (biasp) v += ROWBIAS ? rbias : biasp[cc];
                if (OUTF32) Cfp[(long long)row * ldc + cc] = v;
                else        Cbf[(long long)row * ldc + cc] = f2bf(v);
            }
        }
    }
}

// In-place softmax over rows of 1024 fp32. One 256-thread block per row.
__global__ __launch_bounds__(256)
void softmax_kernel(float* __restrict__ attn)
{
    const long long row = blockIdx.x;
    float* p = attn + row * 1024;
    const int tid  = threadIdx.x;
    const int lane = tid & 63;
    const int wave = tid >> 6;
    __shared__ float red[8];

    f32x4 v = *(f32x4*)(p + tid * 4);
    float mx = fmaxf(fmaxf(v.x, v.y), fmaxf(v.z, v.w));
    #pragma unroll
    for (int off = 1; off < 64; off <<= 1)
        mx = fmaxf(mx, __shfl_xor(mx, off, 64));
    if (lane == 0) red[wave] = mx;
    __syncthreads();
    mx = fmaxf(fmaxf(red[0], red[1]), fmaxf(red[2], red[3]));

    v.x = __expf(v.x - mx);
    v.y = __expf(v.y - mx);
    v.z = __expf(v.z - mx);
    v.w = __expf(v.w - mx);
    float s = v.x + v.y + v.z + v.w;
    #pragma unroll
    for (int off = 1; off < 64; off <<= 1)
        s += __shfl_xor(s, off, 64);
    if (lane == 0) red[4 + wave] = s;
    __syncthreads();
    s = red[4] + red[5] + red[6] + red[7];
    float inv = 1.0f / s;
    v.x *= inv; v.y *= inv; v.z *= inv; v.w *= inv;
    *(f32x4*)(p + tid * 4) = v;
}

// x fp32 -> bf16 elementwise
__global__ __launch_bounds__(256)
void cvt_kernel(const float* __restrict__ in, u16* __restrict__ out)
{
    long long i = (long long)blockIdx.x * 256 + threadIdx.x;
    f32x4 v = *(const f32x4*)(in + i * 4);
    u32x2 p;
    p.x = (unsigned)f2bf(v.x) | ((unsigned)f2bf(v.y) << 16);
    p.y = (unsigned)f2bf(v.z) | ((unsigned)f2bf(v.w) << 16);
    *(u32x2*)(out + i * 4) = p;
}

// transpose fp32 [R][C] -> bf16 [C][R]; 64x64 tiles, grid (C/64, R/64)
__global__ __launch_bounds__(256)
void wtrans_kernel(const float* __restrict__ in, u16* __restrict__ out, int R, int C)
{
    __shared__ __attribute__((aligned(16))) u16 t[64][72];
    const int r0 = blockIdx.y * 64, c0 = blockIdx.x * 64;
    const int tid = threadIdx.x;
    const int lr = tid >> 4;
    const int lc = (tid & 15) << 2;
    #pragma unroll
    for (int j = 0; j < 4; ++j) {
        int rr = lr + j * 16;
        f32x4 v = *(const f32x4*)(in + (long long)(r0 + rr) * C + c0 + lc);
        u32x2 p;
        p.x = (unsigned)f2bf(v.x) | ((unsigned)f2bf(v.y) << 16);
        p.y = (unsigned)f2bf(v.z) | ((unsigned)f2bf(v.w) << 16);
        *(u32x2*)(&t[rr][lc]) = p;
    }
    __syncthreads();
    const int oc = tid >> 2;
    const int rs = (tid & 3) << 4;
    union { short8 v; u16 e[8]; } a, b;
    #pragma unroll
    for (int j = 0; j < 8; ++j) a.e[j] = t[rs + j][oc];
    #pragma unroll
    for (int j = 0; j < 8; ++j) b.e[j] = t[rs + 8 + j][oc];
    u16* o = out + (long long)(c0 + oc) * R + r0 + rs;
    *(short8*)o = a.v;
    *(short8*)(o + 8) = b.v;
}

extern "C" void kernel_launch(void* const* d_in, const int* in_sizes, int n_in,
                              void* d_out, int out_size, void* d_ws, size_t ws_size,
                              hipStream_t stream)
{
    const float* x  = (const float*)d_in[0];
    const float* Wq = (const float*)d_in[1];
    const float* bq = (const float*)d_in[2];
    const float* Wk = (const float*)d_in[3];
    const float* bk = (const float*)d_in[4];
    const float* Wv = (const float*)d_in[5];
    const float* bv = (const float*)d_in[6];
    const float* Wo = (const float*)d_in[7];
    const float* bo = (const float*)d_in[8];

    const int B = 4, S = 1024, D = 512, H = 8;
    const int HD = H * D;   // 4096
    const int BS = B * S;   // 4096

    float* out  = (float*)d_out;                     // [4096, 512]
    float* attn = out + (long long)BS * D;           // [32, 1024, 1024]

    u16* xb   = (u16*)d_ws;                          // [4096,512]
    u16* WqT  = xb  + (long long)BS * D;
    u16* WkT  = WqT + (long long)HD * D;
    u16* WvT  = WkT + (long long)HD * D;
    u16* WoT  = WvT + (long long)HD * D;             // [512,4096]
    u16* buf1 = WoT + (long long)D * HD;             // [4096,4096]
    u16* buf2 = buf1 + (long long)BS * HD;

    dim3 blk(256);

    // 0) prep: x -> bf16, weights -> transposed bf16
    cvt_kernel<<<dim3(BS * D / 1024), blk, 0, stream>>>(x, xb);
    wtrans_kernel<<<dim3(HD / 64, D / 64), blk, 0, stream>>>(Wq, WqT, D, HD);
    wtrans_kernel<<<dim3(HD / 64, D / 64), blk, 0, stream>>>(Wk, WkT, D, HD);
    wtrans_kernel<<<dim3(HD / 64, D / 64), blk, 0, stream>>>(Wv, WvT, D, HD);
    wtrans_kernel<<<dim3(D / 64, HD / 64), blk, 0, stream>>>(Wo, WoT, HD, D);

    // 1) q = xb @ WqT^T -> buf1 ; k = xb @ WkT^T -> buf2   [128x128 tiles]
    {
        dim3 g(HD / 128, BS / 128, 1);
        gemm_bt<4,4,false,false,false><<<g, blk, 0, stream>>>(
            xb, D, 0, 0, WqT, D, 0, 0, buf1, HD, 0, 0, D, bq, 0, 1.0f, 1);
        gemm_bt<4,4,false,false,false><<<g, blk, 0, stream>>>(
            xb, D, 0, 0, WkT, D, 0, 0, buf2, HD, 0, 0, D, bk, 0, 1.0f, 1);
    }
    // 2) scores = q @ k^T / 512 per (h,b) -> fp32 attn region
    {
        dim3 g(S / 128, S / 128, H * B);
        gemm_bt<4,4,false,true,false><<<g, blk, 0, stream>>>(
            buf1, HD, D, (long long)S * HD,
            buf2, HD, D, (long long)S * HD,
            attn, S, (long long)B * S * S, (long long)S * S,
            D, nullptr, 0, 1.0f / (float)D, B);
    }
    // 3) row softmax in place
    softmax_kernel<<<dim3(H * B * S), blk, 0, stream>>>(attn);
    // 4) vT[hb][d][s] = Wv^T slice @ xb^T + bv  -> buf1 (q dead); row bias
    {
        dim3 g(S / 128, D / 128, H * B);
        gemm_bt<4,4,false,false,true><<<g, blk, 0, stream>>>(
            WvT, D, (long long)D * D, 0,
            xb, D, 0, (long long)S * D,
            buf1, S, (long long)B * D * S, (long long)D * S,
            D, bv, D, 1.0f, B);
    }
    // 5) ctx = attn @ vT^T per (h,b) -> buf2 bf16 (k dead)   [128x256 tiles]
    //    A staged raw-fp32 via gl2lds16 + XOR-swizzle, cvt_pk at frag load.
    {
        dim3 g(D / 256, S / 128, H * B);
        gemm_bt<4,8,true,false,false><<<g, blk, 0, stream>>>(
            attn, S, (long long)B * S * S, (long long)S * S,
            buf1, S, (long long)B * D * S, (long long)D * S,
            buf2, HD, D, (long long)S * HD,
            S, nullptr, 0, 1.0f, B);
    }
    // 6) out = ctx @ WoT^T + bo -> fp32   [64x128 tiles, 256 blocks]
    {
        dim3 g(D / 128, BS / 64, 1);
        gemm_bt<2,4,false,true,false><<<g, blk, 0, stream>>>(
            buf2, HD, 0, 0, WoT, HD, 0, 0, out, D, 0, 0, HD, bo, 0, 1.0f, 1);
    }
}

// Round 5
// 518.371 us; speedup vs baseline: 1.1157x; 1.0602x over previous
//
#include <hip/hip_runtime.h>
#include <hip/hip_bf16.h>

// MultiHeadSelfAttention: B=4, S=1024, D=512(d_model = per-head dim), H=8
// out  = [B*S, D]    fp32 at d_out
// attn = [H*B, S, S] fp32 at d_out + B*S*D
//
// All GEMMs are BT (B given as [N][K] bf16, k-contiguous).
// V is computed directly transposed (vT[hb][d][s]) via a row-bias GEMM.
//
// This round (resubmit of round-3 source; round-4 failure was infra-level):
//  - DBUF template flag: bf16 GEMMs keep the double-buffered 1-barrier loop
//    (proven -38us); AF32 step-5 reverts to the single-buffered 2-barrier
//    loop (dbuf regressed it 100->113us: at 2 blocks/CU its latency was
//    already hidden across blocks, dbuf only doubled LDS).
//  - step-5 uses 128x128 tiles: grid 512->1024 blocks (4 blocks/CU) for
//    cross-block latency hiding; attn+vT (167MB) < L3 so re-reads are cheap.
//  - T1 bijective XCD swizzle (m204) on all gemm_bt grids for L2 locality.
//
// d_ws layout (87.1 MB <= 100.7 MB proven available):
//   xb   bf16 [4096,512]    4 MB
//   WqT  bf16 [4096,512]    4 MB
//   WkT  bf16 [4096,512]    4 MB
//   WvT  bf16 [4096,512]    4 MB
//   WoT  bf16 [512,4096]    4 MB
//   buf1 bf16 [4096,4096]  33.5 MB   (q  -> vT)
//   buf2 bf16 [4096,4096]  33.5 MB   (k  -> ctx)

typedef unsigned short u16;
typedef __attribute__((ext_vector_type(8))) short short8;
typedef __attribute__((ext_vector_type(4))) float f32x4;
typedef __attribute__((ext_vector_type(2))) unsigned int u32x2;

#define BK 32

__device__ __forceinline__ u16 f2bf(float f) {
    union { float f; unsigned u; } v; v.f = f;
    unsigned u = v.u;
    u += 0x7fffu + ((u >> 16) & 1u);   // round-to-nearest-even
    return (u16)(u >> 16);
}

__device__ __forceinline__ void gl2lds16(const void* g, void* l) {
    __builtin_amdgcn_global_load_lds(
        (const __attribute__((address_space(1))) void*)g,
        (__attribute__((address_space(3))) void*)l, 16, 0, 0);
}

// C = scale * (A @ B^T) + bias.  A:[M,K] (fp32 or bf16), B:[N,K] bf16.
// Tile: BM=MF*32 x BN=NF*32, 4 waves in 2x2, BK=32, 16x16x32 bf16 MFMA.
// Batch via (swizzled) blockIdx.z: zh = z/nb, zb = z%nb.
// AF32: A tile staged as raw fp32 in LDS (gl2lds16, source-chunk XOR swizzle),
//       converted to bf16 during fragment load (cvt_pk, compute phase).
// DBUF: double-buffered 1-barrier K-loop; else single-buffered 2-barrier.
template<int MF, int NF, bool AF32, bool OUTF32, bool ROWBIAS, bool DBUF>
__global__ __launch_bounds__(256)
void gemm_bt(const void* __restrict__ Ap, int lda, long long sAh, long long sAb,
             const u16* __restrict__ Bp, int ldb, long long sBh, long long sBb,
             void* __restrict__ Cp, int ldc, long long sCh, long long sCb,
             int K, const float* __restrict__ bias, long long sbias,
             float scale, int nb)
{
    constexpr int BMt = MF * 32, BNt = NF * 32;
    constexpr int AW = AF32 ? 2 * BK : BK;   // A row width in u16
    constexpr int NB = DBUF ? 2 : 1;
    // AF32: rows are 32 f32 = 64 u16 = 128 B (8 x 16B chunks, XOR-swizzled)
    __shared__ __attribute__((aligned(16))) u16 Alds[NB][BMt][AW];
    __shared__ __attribute__((aligned(16))) u16 Blds[NB][BNt][BK];

    // T1: bijective XCD-aware remap of the flattened workgroup id (m204).
    int bx = blockIdx.x, by = blockIdx.y, bz = blockIdx.z;
    {
        const int gx = gridDim.x, gy = gridDim.y;
        const int nwg = gx * gy * (int)gridDim.z;
        const int wgid = bx + gx * (by + gy * bz);
        const int xcd = wgid & 7, lp = wgid >> 3;
        const int q = nwg >> 3, r = nwg & 7;
        int nid = (xcd < r ? xcd * (q + 1) : r * (q + 1) + (xcd - r) * q) + lp;
        bx = nid % gx; nid /= gx; by = nid % gy; bz = nid / gy;
    }

    const int zh = bz / nb, zb = bz % nb;
    const int m0 = by * BMt;
    const int n0 = bx * BNt;

    const int tid  = threadIdx.x;
    const int lane = tid & 63;
    const int wave = tid >> 6;
    const int wm = (wave >> 1) * (MF * 16);
    const int wn = (wave & 1) * (NF * 16);

    const float* Afp = (const float*)Ap + (long long)zh * sAh + (long long)zb * sAb;
    const u16*   Abf = (const u16*)Ap + (long long)zh * sAh + (long long)zb * sAb;
    const u16*   Bbf = Bp + (long long)zh * sBh + (long long)zb * sBb;

    f32x4 acc[MF][NF] = {};

    auto stage = [&](int buf, int kt) {
        // ---- stage A tile ----
        if (AF32) {
            // raw fp32 via async global_load_lds; LDS dest linear, global
            // source chunk XOR-swizzled: chunk c of row r holds global
            // k-chunk (c ^ (r&7)).  (both-sides swizzle, involution)
            #pragma unroll
            for (int i = 0; i < BMt / 32; ++i) {
                int idx = i * 256 + tid;      // 16B-chunk index, linear in LDS
                int row = idx >> 3;
                int c   = idx & 7;
                int cs  = c ^ (row & 7);
                gl2lds16(Afp + (long long)(m0 + row) * lda + kt + (cs << 2),
                         (u16*)&Alds[buf][0][0] + idx * 8);
            }
        } else {
            #pragma unroll
            for (int i = 0; i < BMt / 64; ++i) {
                int idx = i * 256 + tid;
                int row = idx >> 2;
                int kq  = (idx & 3) << 3;
                gl2lds16(Abf + (long long)(m0 + row) * lda + (kt + kq),
                         &Alds[buf][row][kq]);
            }
        }
        // ---- stage B tile -> Blds[n][k] ----
        #pragma unroll
        for (int i = 0; i < BNt / 64; ++i) {
            int idx = i * 256 + tid;
            int row = idx >> 2;
            int kq  = (idx & 3) << 3;
            gl2lds16(Bbf + (long long)(n0 + row) * ldb + (kt + kq),
                     &Blds[buf][row][kq]);
        }
    };

    auto compute = [&](int buf) {
        const int kq = (lane >> 4) << 3;
        const int fr = lane & 15;
        short8 af[MF], bfr[NF];
        if (AF32) {
            const int c0 = (lane >> 4) << 1;   // first 16B chunk of my k-slice
            #pragma unroll
            for (int im = 0; im < MF; ++im) {
                int row = wm + im * 16 + fr;
                int s   = row & 7;
                const float* ar = (const float*)&Alds[buf][row][0];
                f32x4 lo = *(const f32x4*)(ar + (((c0    ) ^ s) << 2));
                f32x4 hi = *(const f32x4*)(ar + (((c0 + 1) ^ s) << 2));
                union { short8 v; __hip_bfloat162 h[4]; } a;
                a.h[0] = __float22bfloat162_rn(make_float2(lo.x, lo.y));
                a.h[1] = __float22bfloat162_rn(make_float2(lo.z, lo.w));
                a.h[2] = __float22bfloat162_rn(make_float2(hi.x, hi.y));
                a.h[3] = __float22bfloat162_rn(make_float2(hi.z, hi.w));
                af[im] = a.v;
            }
        } else {
            #pragma unroll
            for (int im = 0; im < MF; ++im)
                af[im] = *(const short8*)(&Alds[buf][wm + im * 16 + fr][kq]);
        }
        #pragma unroll
        for (int in = 0; in < NF; ++in)
            bfr[in] = *(const short8*)(&Blds[buf][wn + in * 16 + fr][kq]);
        #pragma unroll
        for (int im = 0; im < MF; ++im)
            #pragma unroll
            for (int in = 0; in < NF; ++in)
                acc[im][in] = __builtin_amdgcn_mfma_f32_16x16x32_bf16(
                    af[im], bfr[in], acc[im][in], 0, 0, 0);
    };

    const int nt = K / BK;
    if (DBUF) {
        stage(0, 0);                          // prologue prefetch
        for (int t = 0; t < nt; ++t) {
            const int cur = t & 1;
            __syncthreads();                  // vmcnt(0)+barrier: tile t resident
            if (t + 1 < nt)
                stage(cur ^ 1, (t + 1) * BK); // in flight across MFMA phase
            compute(cur);
        }
    } else {
        for (int t = 0; t < nt; ++t) {
            __syncthreads();
            stage(0, t * BK);
            __syncthreads();
            compute(0);
        }
    }

    // ---- epilogue: C[row=(lane>>4)*4+r][col=lane&15] ----
    float* Cfp = (float*)Cp + (long long)zh * sCh + (long long)zb * sCb;
    u16*   Cbf = (u16*)Cp + (long long)zh * sCh + (long long)zb * sCb;
    const float* biasp = bias ? bias + (long long)zh * sbias : nullptr;
    const int rb  = (lane >> 4) << 2;
    const int col = lane & 15;
    #pragma unroll
    for (int im = 0; im < MF; ++im) {
        #pragma unroll
        for (int r = 0; r < 4; ++r) {
            int row = m0 + wm + im * 16 + rb + r;
            float rbias = (biasp && ROWBIAS) ? biasp[row] : 0.0f;
            #pragma unroll
            for (int in = 0; in < NF; ++in) {
                int cc = n0 + wn + in * 16 + col;
                float v = acc[im][in][r] * scale;
                if (biasp) v += ROWBIAS ? rbias : biasp[cc];
                if (OUTF32) Cfp[(long long)row * ldc + cc] = v;
                else        Cbf[(long long)row * ldc + cc] = f2bf(v);
            }
        }
    }
}

// In-place softmax over rows of 1024 fp32. One 256-thread block per row.
__global__ __launch_bounds__(256)
void softmax_kernel(float* __restrict__ attn)
{
    const long long row = blockIdx.x;
    float* p = attn + row * 1024;
    const int tid  = threadIdx.x;
    const int lane = tid & 63;
    const int wave = tid >> 6;
    __shared__ float red[8];

    f32x4 v = *(f32x4*)(p + tid * 4);
    float mx = fmaxf(fmaxf(v.x, v.y), fmaxf(v.z, v.w));
    #pragma unroll
    for (int off = 1; off < 64; off <<= 1)
        mx = fmaxf(mx, __shfl_xor(mx, off, 64));
    if (lane == 0) red[wave] = mx;
    __syncthreads();
    mx = fmaxf(fmaxf(red[0], red[1]), fmaxf(red[2], red[3]));

    v.x = __expf(v.x - mx);
    v.y = __expf(v.y - mx);
    v.z = __expf(v.z - mx);
    v.w = __expf(v.w - mx);
    float s = v.x + v.y + v.z + v.w;
    #pragma unroll
    for (int off = 1; off < 64; off <<= 1)
        s += __shfl_xor(s, off, 64);
    if (lane == 0) red[4 + wave] = s;
    __syncthreads();
    s = red[4] + red[5] + red[6] + red[7];
    float inv = 1.0f / s;
    v.x *= inv; v.y *= inv; v.z *= inv; v.w *= inv;
    *(f32x4*)(p + tid * 4) = v;
}

// x fp32 -> bf16 elementwise
__global__ __launch_bounds__(256)
void cvt_kernel(const float* __restrict__ in, u16* __restrict__ out)
{
    long long i = (long long)blockIdx.x * 256 + threadIdx.x;
    f32x4 v = *(const f32x4*)(in + i * 4);
    u32x2 p;
    p.x = (unsigned)f2bf(v.x) | ((unsigned)f2bf(v.y) << 16);
    p.y = (unsigned)f2bf(v.z) | ((unsigned)f2bf(v.w) << 16);
    *(u32x2*)(out + i * 4) = p;
}

// transpose fp32 [R][C] -> bf16 [C][R]; 64x64 tiles, grid (C/64, R/64)
__global__ __launch_bounds__(256)
void wtrans_kernel(const float* __restrict__ in, u16* __restrict__ out, int R, int C)
{
    __shared__ __attribute__((aligned(16))) u16 t[64][72];
    const int r0 = blockIdx.y * 64, c0 = blockIdx.x * 64;
    const int tid = threadIdx.x;
    const int lr = tid >> 4;
    const int lc = (tid & 15) << 2;
    #pragma unroll
    for (int j = 0; j < 4; ++j) {
        int rr = lr + j * 16;
        f32x4 v = *(const f32x4*)(in + (long long)(r0 + rr) * C + c0 + lc);
        u32x2 p;
        p.x = (unsigned)f2bf(v.x) | ((unsigned)f2bf(v.y) << 16);
        p.y = (unsigned)f2bf(v.z) | ((unsigned)f2bf(v.w) << 16);
        *(u32x2*)(&t[rr][lc]) = p;
    }
    __syncthreads();
    const int oc = tid >> 2;
    const int rs = (tid & 3) << 4;
    union { short8 v; u16 e[8]; } a, b;
    #pragma unroll
    for (int j = 0; j < 8; ++j) a.e[j] = t[rs + j][oc];
    #pragma unroll
    for (int j = 0; j < 8; ++j) b.e[j] = t[rs + 8 + j][oc];
    u16* o = out + (long long)(c0 + oc) * R + r0 + rs;
    *(short8*)o = a.v;
    *(short8*)(o + 8) = b.v;
}

extern "C" void kernel_launch(void* const* d_in, const int* in_sizes, int n_in,
                              void* d_out, int out_size, void* d_ws, size_t ws_size,
                              hipStream_t stream)
{
    const float* x  = (const float*)d_in[0];
    const float* Wq = (const float*)d_in[1];
    const float* bq = (const float*)d_in[2];
    const float* Wk = (const float*)d_in[3];
    const float* bk = (const float*)d_in[4];
    const float* Wv = (const float*)d_in[5];
    const float* bv = (const float*)d_in[6];
    const float* Wo = (const float*)d_in[7];
    const float* bo = (const float*)d_in[8];

    const int B = 4, S = 1024, D = 512, H = 8;
    const int HD = H * D;   // 4096
    const int BS = B * S;   // 4096

    float* out  = (float*)d_out;                     // [4096, 512]
    float* attn = out + (long long)BS * D;           // [32, 1024, 1024]

    u16* xb   = (u16*)d_ws;                          // [4096,512]
    u16* WqT  = xb  + (long long)BS * D;
    u16* WkT  = WqT + (long long)HD * D;
    u16* WvT  = WkT + (long long)HD * D;
    u16* WoT  = WvT + (long long)HD * D;             // [512,4096]
    u16* buf1 = WoT + (long long)D * HD;             // [4096,4096]
    u16* buf2 = buf1 + (long long)BS * HD;

    dim3 blk(256);

    // 0) prep: x -> bf16, weights -> transposed bf16
    cvt_kernel<<<dim3(BS * D / 1024), blk, 0, stream>>>(x, xb);
    wtrans_kernel<<<dim3(HD / 64, D / 64), blk, 0, stream>>>(Wq, WqT, D, HD);
    wtrans_kernel<<<dim3(HD / 64, D / 64), blk, 0, stream>>>(Wk, WkT, D, HD);
    wtrans_kernel<<<dim3(HD / 64, D / 64), blk, 0, stream>>>(Wv, WvT, D, HD);
    wtrans_kernel<<<dim3(D / 64, HD / 64), blk, 0, stream>>>(Wo, WoT, HD, D);

    // 1) q = xb @ WqT^T -> buf1 ; k = xb @ WkT^T -> buf2   [128x128 tiles]
    {
        dim3 g(HD / 128, BS / 128, 1);
        gemm_bt<4,4,false,false,false,true><<<g, blk, 0, stream>>>(
            xb, D, 0, 0, WqT, D, 0, 0, buf1, HD, 0, 0, D, bq, 0, 1.0f, 1);
        gemm_bt<4,4,false,false,false,true><<<g, blk, 0, stream>>>(
            xb, D, 0, 0, WkT, D, 0, 0, buf2, HD, 0, 0, D, bk, 0, 1.0f, 1);
    }
    // 2) scores = q @ k^T / 512 per (h,b) -> fp32 attn region
    {
        dim3 g(S / 128, S / 128, H * B);
        gemm_bt<4,4,false,true,false,true><<<g, blk, 0, stream>>>(
            buf1, HD, D, (long long)S * HD,
            buf2, HD, D, (long long)S * HD,
            attn, S, (long long)B * S * S, (long long)S * S,
            D, nullptr, 0, 1.0f / (float)D, B);
    }
    // 3) row softmax in place
    softmax_kernel<<<dim3(H * B * S), blk, 0, stream>>>(attn);
    // 4) vT[hb][d][s] = Wv^T slice @ xb^T + bv  -> buf1 (q dead); row bias
    {
        dim3 g(S / 128, D / 128, H * B);
        gemm_bt<4,4,false,false,true,true><<<g, blk, 0, stream>>>(
            WvT, D, (long long)D * D, 0,
            xb, D, 0, (long long)S * D,
            buf1, S, (long long)B * D * S, (long long)D * S,
            D, bv, D, 1.0f, B);
    }
    // 5) ctx = attn @ vT^T per (h,b) -> buf2 bf16 (k dead)   [128x128 tiles]
    //    A staged raw-fp32 via gl2lds16 + XOR-swizzle, cvt_pk at frag load.
    //    Single-buffered (2 blocks/CU case regressed with dbuf); 1024 blocks.
    {
        dim3 g(D / 128, S / 128, H * B);
        gemm_bt<4,4,true,false,false,false><<<g, blk, 0, stream>>>(
            attn, S, (long long)B * S * S, (long long)S * S,
            buf1, S, (long long)B * D * S, (long long)D * S,
            buf2, HD, D, (long long)S * HD,
            S, nullptr, 0, 1.0f, B);
    }
    // 6) out = ctx @ WoT^T + bo -> fp32   [64x128 tiles, 256 blocks]
    {
        dim3 g(D / 128, BS / 64, 1);
        gemm_bt<2,4,false,true,false,true><<<g, blk, 0, stream>>>(
            buf2, HD, 0, 0, WoT, HD, 0, 0, out, D, 0, 0, HD, bo, 0, 1.0f, 1);
    }
}

// Round 6
// 510.852 us; speedup vs baseline: 1.1321x; 1.0147x over previous
//
#include <hip/hip_runtime.h>
#include <hip/hip_bf16.h>

// MultiHeadSelfAttention: B=4, S=1024, D=512(d_model = per-head dim), H=8
// out  = [B*S, D]    fp32 at d_out
// attn = [H*B, S, S] fp32 at d_out + B*S*D
//
// All GEMMs are BT (B given as [N][K] bf16, k-contiguous).
// V is computed directly transposed (vT[hb][d][s]) via a row-bias GEMM.
//
// This round: bf16 GEMMs move from 2-deep __syncthreads dbuf to a 3-buffer
// counted-vmcnt pipeline (T4): raw s_barrier (no implicit vmcnt(0) drain),
// steady-state s_waitcnt vmcnt(LPT) keeps one tile's global_load_lds in
// flight across the barrier; stage(t+2) issued after the barrier (buffer
// (t+2)%3 == (t-1)%3 proven read-complete). AF32 step-5 keeps the proven
// single-buffer 2-barrier loop. Step-6 reshaped to 512 blocks (BN=64).
//
// d_ws layout (87.1 MB <= 100.7 MB proven available):
//   xb   bf16 [4096,512]    4 MB
//   WqT  bf16 [4096,512]    4 MB
//   WkT  bf16 [4096,512]    4 MB
//   WvT  bf16 [4096,512]    4 MB
//   WoT  bf16 [512,4096]    4 MB
//   buf1 bf16 [4096,4096]  33.5 MB   (q  -> vT)
//   buf2 bf16 [4096,4096]  33.5 MB   (k  -> ctx)

typedef unsigned short u16;
typedef __attribute__((ext_vector_type(8))) short short8;
typedef __attribute__((ext_vector_type(4))) float f32x4;
typedef __attribute__((ext_vector_type(2))) unsigned int u32x2;

#define BK 32

__device__ __forceinline__ u16 f2bf(float f) {
    union { float f; unsigned u; } v; v.f = f;
    unsigned u = v.u;
    u += 0x7fffu + ((u >> 16) & 1u);   // round-to-nearest-even
    return (u16)(u >> 16);
}

__device__ __forceinline__ void gl2lds16(const void* g, void* l) {
    __builtin_amdgcn_global_load_lds(
        (const __attribute__((address_space(1))) void*)g,
        (__attribute__((address_space(3))) void*)l, 16, 0, 0);
}

// C = scale * (A @ B^T) + bias.  A:[M,K] (fp32 or bf16), B:[N,K] bf16.
// Tile: BM=MF*32 x BN=NF*32, 4 waves in 2x2, BK=32, 16x16x32 bf16 MFMA.
// Batch via (swizzled) blockIdx.z: zh = z/nb, zb = z%nb.
// AF32: A tile staged as raw fp32 in LDS (gl2lds16, source-chunk XOR swizzle),
//       converted to bf16 during fragment load (cvt_pk, compute phase).
// PIPE: 3-buffer counted-vmcnt pipeline (bf16-A only); else single-buffered.
template<int MF, int NF, bool AF32, bool OUTF32, bool ROWBIAS, bool PIPE>
__global__ __launch_bounds__(256)
void gemm_bt(const void* __restrict__ Ap, int lda, long long sAh, long long sAb,
             const u16* __restrict__ Bp, int ldb, long long sBh, long long sBb,
             void* __restrict__ Cp, int ldc, long long sCh, long long sCb,
             int K, const float* __restrict__ bias, long long sbias,
             float scale, int nb)
{
    static_assert(!(PIPE && AF32), "PIPE path assumes bf16 A staging");
    constexpr int BMt = MF * 32, BNt = NF * 32;
    constexpr int AW = AF32 ? 2 * BK : BK;   // A row width in u16
    constexpr int NBUF = PIPE ? 3 : 1;
    constexpr int LPT = BMt / 64 + BNt / 64; // gl2lds per thread per stage (bf16)
    __shared__ __attribute__((aligned(16))) u16 Alds[NBUF][BMt][AW];
    __shared__ __attribute__((aligned(16))) u16 Blds[NBUF][BNt][BK];

    // T1: bijective XCD-aware remap of the flattened workgroup id (m204).
    int bx = blockIdx.x, by = blockIdx.y, bz = blockIdx.z;
    {
        const int gx = gridDim.x, gy = gridDim.y;
        const int nwg = gx * gy * (int)gridDim.z;
        const int wgid = bx + gx * (by + gy * bz);
        const int xcd = wgid & 7, lp = wgid >> 3;
        const int q = nwg >> 3, r = nwg & 7;
        int nid = (xcd < r ? xcd * (q + 1) : r * (q + 1) + (xcd - r) * q) + lp;
        bx = nid % gx; nid /= gx; by = nid % gy; bz = nid / gy;
    }

    const int zh = bz / nb, zb = bz % nb;
    const int m0 = by * BMt;
    const int n0 = bx * BNt;

    const int tid  = threadIdx.x;
    const int lane = tid & 63;
    const int wave = tid >> 6;
    const int wm = (wave >> 1) * (MF * 16);
    const int wn = (wave & 1) * (NF * 16);

    const float* Afp = (const float*)Ap + (long long)zh * sAh + (long long)zb * sAb;
    const u16*   Abf = (const u16*)Ap + (long long)zh * sAh + (long long)zb * sAb;
    const u16*   Bbf = Bp + (long long)zh * sBh + (long long)zb * sBb;

    f32x4 acc[MF][NF] = {};

    auto stage = [&](int buf, int kt) {
        // ---- stage A tile ----
        if (AF32) {
            // raw fp32 via async global_load_lds; LDS dest linear, global
            // source chunk XOR-swizzled: chunk c of row r holds global
            // k-chunk (c ^ (r&7)).  (both-sides swizzle, involution)
            #pragma unroll
            for (int i = 0; i < BMt / 32; ++i) {
                int idx = i * 256 + tid;      // 16B-chunk index, linear in LDS
                int row = idx >> 3;
                int c   = idx & 7;
                int cs  = c ^ (row & 7);
                gl2lds16(Afp + (long long)(m0 + row) * lda + kt + (cs << 2),
                         (u16*)&Alds[buf][0][0] + idx * 8);
            }
        } else {
            #pragma unroll
            for (int i = 0; i < BMt / 64; ++i) {
                int idx = i * 256 + tid;
                int row = idx >> 2;
                int kq  = (idx & 3) << 3;
                gl2lds16(Abf + (long long)(m0 + row) * lda + (kt + kq),
                         &Alds[buf][row][kq]);
            }
        }
        // ---- stage B tile -> Blds[n][k] ----
        #pragma unroll
        for (int i = 0; i < BNt / 64; ++i) {
            int idx = i * 256 + tid;
            int row = idx >> 2;
            int kq  = (idx & 3) << 3;
            gl2lds16(Bbf + (long long)(n0 + row) * ldb + (kt + kq),
                     &Blds[buf][row][kq]);
        }
    };

    auto compute = [&](int buf) {
        const int kq = (lane >> 4) << 3;
        const int fr = lane & 15;
        short8 af[MF], bfr[NF];
        if (AF32) {
            const int c0 = (lane >> 4) << 1;   // first 16B chunk of my k-slice
            #pragma unroll
            for (int im = 0; im < MF; ++im) {
                int row = wm + im * 16 + fr;
                int s   = row & 7;
                const float* ar = (const float*)&Alds[buf][row][0];
                f32x4 lo = *(const f32x4*)(ar + (((c0    ) ^ s) << 2));
                f32x4 hi = *(const f32x4*)(ar + (((c0 + 1) ^ s) << 2));
                union { short8 v; __hip_bfloat162 h[4]; } a;
                a.h[0] = __float22bfloat162_rn(make_float2(lo.x, lo.y));
                a.h[1] = __float22bfloat162_rn(make_float2(lo.z, lo.w));
                a.h[2] = __float22bfloat162_rn(make_float2(hi.x, hi.y));
                a.h[3] = __float22bfloat162_rn(make_float2(hi.z, hi.w));
                af[im] = a.v;
            }
        } else {
            #pragma unroll
            for (int im = 0; im < MF; ++im)
                af[im] = *(const short8*)(&Alds[buf][wm + im * 16 + fr][kq]);
        }
        #pragma unroll
        for (int in = 0; in < NF; ++in)
            bfr[in] = *(const short8*)(&Blds[buf][wn + in * 16 + fr][kq]);
        #pragma unroll
        for (int im = 0; im < MF; ++im)
            #pragma unroll
            for (int in = 0; in < NF; ++in)
                acc[im][in] = __builtin_amdgcn_mfma_f32_16x16x32_bf16(
                    af[im], bfr[in], acc[im][in], 0, 0, 0);
    };

    const int nt = K / BK;
    if (PIPE) {
        // 3-buffer counted-vmcnt pipeline. Invariant at top of iter t:
        // tiles t (LPT loads) and t+1 (LPT) outstanding per wave.
        // vmcnt(LPT) retires tile t (oldest-first); raw barrier then proves
        // all waves' tile-t loads landed. stage(t+2) goes AFTER the barrier
        // because buffer (t+2)%3 == (t-1)%3 was read in compute(t-1).
        stage(0, 0);
        stage(1, BK);
        for (int t = 0; t < nt; ++t) {
            if (t < nt - 1) {
                if constexpr (LPT == 4)
                    asm volatile("s_waitcnt vmcnt(4)" ::: "memory");
                else if constexpr (LPT == 3)
                    asm volatile("s_waitcnt vmcnt(3)" ::: "memory");
                else if constexpr (LPT == 2)
                    asm volatile("s_waitcnt vmcnt(2)" ::: "memory");
                else
                    asm volatile("s_waitcnt vmcnt(0)" ::: "memory");
            } else {
                asm volatile("s_waitcnt vmcnt(0)" ::: "memory");
            }
            __builtin_amdgcn_s_barrier();
            __builtin_amdgcn_sched_barrier(0);
            const int nx = t + 2;
            if (nx < nt) stage(nx - nx / 3 * 3, nx * BK);
            compute(t - t / 3 * 3);
        }
        __builtin_amdgcn_s_barrier();   // all reads done before block exits
    } else {
        for (int t = 0; t < nt; ++t) {
            __syncthreads();
            stage(0, t * BK);
            __syncthreads();
            compute(0);
        }
    }

    // ---- epilogue: C[row=(lane>>4)*4+r][col=lane&15] ----
    float* Cfp = (float*)Cp + (long long)zh * sCh + (long long)zb * sCb;
    u16*   Cbf = (u16*)Cp + (long long)zh * sCh + (long long)zb * sCb;
    const float* biasp = bias ? bias + (long long)zh * sbias : nullptr;
    const int rb  = (lane >> 4) << 2;
    const int col = lane & 15;
    #pragma unroll
    for (int im = 0; im < MF; ++im) {
        #pragma unroll
        for (int r = 0; r < 4; ++r) {
            int row = m0 + wm + im * 16 + rb + r;
            float rbias = (biasp && ROWBIAS) ? biasp[row] : 0.0f;
            #pragma unroll
            for (int in = 0; in < NF; ++in) {
                int cc = n0 + wn + in * 16 + col;
                float v = acc[im][in][r] * scale;
                if (biasp) v += ROWBIAS ? rbias : biasp[cc];
                if (OUTF32) Cfp[(long long)row * ldc + cc] = v;
                else        Cbf[(long long)row * ldc + cc] = f2bf(v);
            }
        }
    }
}

// In-place softmax over rows of 1024 fp32. One 256-thread block per row.
__global__ __launch_bounds__(256)
void softmax_kernel(float* __restrict__ attn)
{
    const long long row = blockIdx.x;
    float* p = attn + row * 1024;
    const int tid  = threadIdx.x;
    const int lane = tid & 63;
    const int wave = tid >> 6;
    __shared__ float red[8];

    f32x4 v = *(f32x4*)(p + tid * 4);
    float mx = fmaxf(fmaxf(v.x, v.y), fmaxf(v.z, v.w));
    #pragma unroll
    for (int off = 1; off < 64; off <<= 1)
        mx = fmaxf(mx, __shfl_xor(mx, off, 64));
    if (lane == 0) red[wave] = mx;
    __syncthreads();
    mx = fmaxf(fmaxf(red[0], red[1]), fmaxf(red[2], red[3]));

    v.x = __expf(v.x - mx);
    v.y = __expf(v.y - mx);
    v.z = __expf(v.z - mx);
    v.w = __expf(v.w - mx);
    float s = v.x + v.y + v.z + v.w;
    #pragma unroll
    for (int off = 1; off < 64; off <<= 1)
        s += __shfl_xor(s, off, 64);
    if (lane == 0) red[4 + wave] = s;
    __syncthreads();
    s = red[4] + red[5] + red[6] + red[7];
    float inv = 1.0f / s;
    v.x *= inv; v.y *= inv; v.z *= inv; v.w *= inv;
    *(f32x4*)(p + tid * 4) = v;
}

// x fp32 -> bf16 elementwise
__global__ __launch_bounds__(256)
void cvt_kernel(const float* __restrict__ in, u16* __restrict__ out)
{
    long long i = (long long)blockIdx.x * 256 + threadIdx.x;
    f32x4 v = *(const f32x4*)(in + i * 4);
    u32x2 p;
    p.x = (unsigned)f2bf(v.x) | ((unsigned)f2bf(v.y) << 16);
    p.y = (unsigned)f2bf(v.z) | ((unsigned)f2bf(v.w) << 16);
    *(u32x2*)(out + i * 4) = p;
}

// transpose fp32 [R][C] -> bf16 [C][R]; 64x64 tiles, grid (C/64, R/64)
__global__ __launch_bounds__(256)
void wtrans_kernel(const float* __restrict__ in, u16* __restrict__ out, int R, int C)
{
    __shared__ __attribute__((aligned(16))) u16 t[64][72];
    const int r0 = blockIdx.y * 64, c0 = blockIdx.x * 64;
    const int tid = threadIdx.x;
    const int lr = tid >> 4;
    const int lc = (tid & 15) << 2;
    #pragma unroll
    for (int j = 0; j < 4; ++j) {
        int rr = lr + j * 16;
        f32x4 v = *(const f32x4*)(in + (long long)(r0 + rr) * C + c0 + lc);
        u32x2 p;
        p.x = (unsigned)f2bf(v.x) | ((unsigned)f2bf(v.y) << 16);
        p.y = (unsigned)f2bf(v.z) | ((unsigned)f2bf(v.w) << 16);
        *(u32x2*)(&t[rr][lc]) = p;
    }
    __syncthreads();
    const int oc = tid >> 2;
    const int rs = (tid & 3) << 4;
    union { short8 v; u16 e[8]; } a, b;
    #pragma unroll
    for (int j = 0; j < 8; ++j) a.e[j] = t[rs + j][oc];
    #pragma unroll
    for (int j = 0; j < 8; ++j) b.e[j] = t[rs + 8 + j][oc];
    u16* o = out + (long long)(c0 + oc) * R + r0 + rs;
    *(short8*)o = a.v;
    *(short8*)(o + 8) = b.v;
}

extern "C" void kernel_launch(void* const* d_in, const int* in_sizes, int n_in,
                              void* d_out, int out_size, void* d_ws, size_t ws_size,
                              hipStream_t stream)
{
    const float* x  = (const float*)d_in[0];
    const float* Wq = (const float*)d_in[1];
    const float* bq = (const float*)d_in[2];
    const float* Wk = (const float*)d_in[3];
    const float* bk = (const float*)d_in[4];
    const float* Wv = (const float*)d_in[5];
    const float* bv = (const float*)d_in[6];
    const float* Wo = (const float*)d_in[7];
    const float* bo = (const float*)d_in[8];

    const int B = 4, S = 1024, D = 512, H = 8;
    const int HD = H * D;   // 4096
    const int BS = B * S;   // 4096

    float* out  = (float*)d_out;                     // [4096, 512]
    float* attn = out + (long long)BS * D;           // [32, 1024, 1024]

    u16* xb   = (u16*)d_ws;                          // [4096,512]
    u16* WqT  = xb  + (long long)BS * D;
    u16* WkT  = WqT + (long long)HD * D;
    u16* WvT  = WkT + (long long)HD * D;
    u16* WoT  = WvT + (long long)HD * D;             // [512,4096]
    u16* buf1 = WoT + (long long)D * HD;             // [4096,4096]
    u16* buf2 = buf1 + (long long)BS * HD;

    dim3 blk(256);

    // 0) prep: x -> bf16, weights -> transposed bf16
    cvt_kernel<<<dim3(BS * D / 1024), blk, 0, stream>>>(x, xb);
    wtrans_kernel<<<dim3(HD / 64, D / 64), blk, 0, stream>>>(Wq, WqT, D, HD);
    wtrans_kernel<<<dim3(HD / 64, D / 64), blk, 0, stream>>>(Wk, WkT, D, HD);
    wtrans_kernel<<<dim3(HD / 64, D / 64), blk, 0, stream>>>(Wv, WvT, D, HD);
    wtrans_kernel<<<dim3(D / 64, HD / 64), blk, 0, stream>>>(Wo, WoT, HD, D);

    // 1) q = xb @ WqT^T -> buf1 ; k = xb @ WkT^T -> buf2   [128x128 tiles]
    {
        dim3 g(HD / 128, BS / 128, 1);
        gemm_bt<4,4,false,false,false,true><<<g, blk, 0, stream>>>(
            xb, D, 0, 0, WqT, D, 0, 0, buf1, HD, 0, 0, D, bq, 0, 1.0f, 1);
        gemm_bt<4,4,false,false,false,true><<<g, blk, 0, stream>>>(
            xb, D, 0, 0, WkT, D, 0, 0, buf2, HD, 0, 0, D, bk, 0, 1.0f, 1);
    }
    // 2) scores = q @ k^T / 512 per (h,b) -> fp32 attn region
    {
        dim3 g(S / 128, S / 128, H * B);
        gemm_bt<4,4,false,true,false,true><<<g, blk, 0, stream>>>(
            buf1, HD, D, (long long)S * HD,
            buf2, HD, D, (long long)S * HD,
            attn, S, (long long)B * S * S, (long long)S * S,
            D, nullptr, 0, 1.0f / (float)D, B);
    }
    // 3) row softmax in place
    softmax_kernel<<<dim3(H * B * S), blk, 0, stream>>>(attn);
    // 4) vT[hb][d][s] = Wv^T slice @ xb^T + bv  -> buf1 (q dead); row bias
    {
        dim3 g(S / 128, D / 128, H * B);
        gemm_bt<4,4,false,false,true,true><<<g, blk, 0, stream>>>(
            WvT, D, (long long)D * D, 0,
            xb, D, 0, (long long)S * D,
            buf1, S, (long long)B * D * S, (long long)D * S,
            D, bv, D, 1.0f, B);
    }
    // 5) ctx = attn @ vT^T per (h,b) -> buf2 bf16 (k dead)   [128x128 tiles]
    //    A staged raw-fp32 via gl2lds16 + XOR-swizzle, cvt_pk at frag load.
    //    Single-buffered (proven best for this one); 1024 blocks.
    {
        dim3 g(D / 128, S / 128, H * B);
        gemm_bt<4,4,true,false,false,false><<<g, blk, 0, stream>>>(
            attn, S, (long long)B * S * S, (long long)S * S,
            buf1, S, (long long)B * D * S, (long long)D * S,
            buf2, HD, D, (long long)S * HD,
            S, nullptr, 0, 1.0f, B);
    }
    // 6) out = ctx @ WoT^T + bo -> fp32   [64x64 tiles, 512 blocks]
    {
        dim3 g(D / 64, BS / 64, 1);
        gemm_bt<2,2,false,true,false,true><<<g, blk, 0, stream>>>(
            buf2, HD, 0, 0, WoT, HD, 0, 0, out, D, 0, 0, HD, bo, 0, 1.0f, 1);
    }
}

// Round 7
// 479.623 us; speedup vs baseline: 1.2059x; 1.0651x over previous
//
#include <hip/hip_runtime.h>
#include <hip/hip_bf16.h>

// MultiHeadSelfAttention: B=4, S=1024, D=512(d_model = per-head dim), H=8
// out  = [B*S, D]    fp32 at d_out
// attn = [H*B, S, S] fp32 at d_out + B*S*D
//
// All GEMMs are BT (B given as [N][K] bf16, k-contiguous).
// V is computed directly transposed (vT[hb][d][s]) via a row-bias GEMM.
//
// This round:
//  - __launch_bounds__(256,4): cap VGPRs at 128 (was 136) -> 4 blocks/CU on
//    the VGPR-capped kernels (step-5 AF32 especially; PIPE kernels stay
//    LDS-capped at 3).
//  - q and k projections fused into ONE GEMM over the stacked [8192,512]
//    B = [WqT;WkT] (contiguous in ws); DUALN epilogue routes n>=4096 to
//    buf2/bk. One fewer launch + one fewer grid tail.
//
// d_ws layout (87.1 MB <= 100.7 MB proven available):
//   xb   bf16 [4096,512]    4 MB
//   WqT  bf16 [4096,512]    4 MB
//   WkT  bf16 [4096,512]    4 MB   (contiguous after WqT -> stacked B)
//   WvT  bf16 [4096,512]    4 MB
//   WoT  bf16 [512,4096]    4 MB
//   buf1 bf16 [4096,4096]  33.5 MB   (q  -> vT)
//   buf2 bf16 [4096,4096]  33.5 MB   (k  -> ctx)

typedef unsigned short u16;
typedef __attribute__((ext_vector_type(8))) short short8;
typedef __attribute__((ext_vector_type(4))) float f32x4;
typedef __attribute__((ext_vector_type(2))) unsigned int u32x2;

#define BK 32

__device__ __forceinline__ u16 f2bf(float f) {
    union { float f; unsigned u; } v; v.f = f;
    unsigned u = v.u;
    u += 0x7fffu + ((u >> 16) & 1u);   // round-to-nearest-even
    return (u16)(u >> 16);
}

__device__ __forceinline__ void gl2lds16(const void* g, void* l) {
    __builtin_amdgcn_global_load_lds(
        (const __attribute__((address_space(1))) void*)g,
        (__attribute__((address_space(3))) void*)l, 16, 0, 0);
}

// C = scale * (A @ B^T) + bias.  A:[M,K] (fp32 or bf16), B:[N,K] bf16.
// Tile: BM=MF*32 x BN=NF*32, 4 waves in 2x2, BK=32, 16x16x32 bf16 MFMA.
// Batch via (swizzled) blockIdx.z: zh = z/nb, zb = z%nb.
// AF32: A tile staged as raw fp32 in LDS (gl2lds16, source-chunk XOR swizzle),
//       converted to bf16 during fragment load (cvt_pk, compute phase).
// PIPE: 3-buffer counted-vmcnt pipeline (bf16-A only); else single-buffered.
// DUALN: B is two stacked weight matrices; columns n>=nsplit write to
//        Cp2 with bias2 (block-uniform select; n0 is a multiple of BN).
template<int MF, int NF, bool AF32, bool OUTF32, bool ROWBIAS, bool PIPE, bool DUALN>
__global__ __launch_bounds__(256, 4)
void gemm_bt(const void* __restrict__ Ap, int lda, long long sAh, long long sAb,
             const u16* __restrict__ Bp, int ldb, long long sBh, long long sBb,
             void* __restrict__ Cp, int ldc, long long sCh, long long sCb,
             int K, const float* __restrict__ bias, long long sbias,
             float scale, int nb,
             int nsplit, void* __restrict__ Cp2, const float* __restrict__ bias2)
{
    static_assert(!(PIPE && AF32), "PIPE path assumes bf16 A staging");
    constexpr int BMt = MF * 32, BNt = NF * 32;
    constexpr int AW = AF32 ? 2 * BK : BK;   // A row width in u16
    constexpr int NBUF = PIPE ? 3 : 1;
    constexpr int LPT = BMt / 64 + BNt / 64; // gl2lds per thread per stage (bf16)
    __shared__ __attribute__((aligned(16))) u16 Alds[NBUF][BMt][AW];
    __shared__ __attribute__((aligned(16))) u16 Blds[NBUF][BNt][BK];

    // T1: bijective XCD-aware remap of the flattened workgroup id (m204).
    int bx = blockIdx.x, by = blockIdx.y, bz = blockIdx.z;
    {
        const int gx = gridDim.x, gy = gridDim.y;
        const int nwg = gx * gy * (int)gridDim.z;
        const int wgid = bx + gx * (by + gy * bz);
        const int xcd = wgid & 7, lp = wgid >> 3;
        const int q = nwg >> 3, r = nwg & 7;
        int nid = (xcd < r ? xcd * (q + 1) : r * (q + 1) + (xcd - r) * q) + lp;
        bx = nid % gx; nid /= gx; by = nid % gy; bz = nid / gy;
    }

    const int zh = bz / nb, zb = bz % nb;
    const int m0 = by * BMt;
    const int n0 = bx * BNt;     // global n (indexes B rows)

    const int tid  = threadIdx.x;
    const int lane = tid & 63;
    const int wave = tid >> 6;
    const int wm = (wave >> 1) * (MF * 16);
    const int wn = (wave & 1) * (NF * 16);

    const float* Afp = (const float*)Ap + (long long)zh * sAh + (long long)zb * sAb;
    const u16*   Abf = (const u16*)Ap + (long long)zh * sAh + (long long)zb * sAb;
    const u16*   Bbf = Bp + (long long)zh * sBh + (long long)zb * sBb;

    // DUALN: route output half (block-uniform since n0 % BNt == 0)
    void* Csel = Cp;
    const float* bsel = bias;
    int nC = n0;
    if (DUALN && n0 >= nsplit) { Csel = Cp2; bsel = bias2; nC = n0 - nsplit; }

    f32x4 acc[MF][NF] = {};

    auto stage = [&](int buf, int kt) {
        // ---- stage A tile ----
        if (AF32) {
            // raw fp32 via async global_load_lds; LDS dest linear, global
            // source chunk XOR-swizzled: chunk c of row r holds global
            // k-chunk (c ^ (r&7)).  (both-sides swizzle, involution)
            #pragma unroll
            for (int i = 0; i < BMt / 32; ++i) {
                int idx = i * 256 + tid;      // 16B-chunk index, linear in LDS
                int row = idx >> 3;
                int c   = idx & 7;
                int cs  = c ^ (row & 7);
                gl2lds16(Afp + (long long)(m0 + row) * lda + kt + (cs << 2),
                         (u16*)&Alds[buf][0][0] + idx * 8);
            }
        } else {
            #pragma unroll
            for (int i = 0; i < BMt / 64; ++i) {
                int idx = i * 256 + tid;
                int row = idx >> 2;
                int kq  = (idx & 3) << 3;
                gl2lds16(Abf + (long long)(m0 + row) * lda + (kt + kq),
                         &Alds[buf][row][kq]);
            }
        }
        // ---- stage B tile -> Blds[n][k] ----
        #pragma unroll
        for (int i = 0; i < BNt / 64; ++i) {
            int idx = i * 256 + tid;
            int row = idx >> 2;
            int kq  = (idx & 3) << 3;
            gl2lds16(Bbf + (long long)(n0 + row) * ldb + (kt + kq),
                     &Blds[buf][row][kq]);
        }
    };

    auto compute = [&](int buf) {
        const int kq = (lane >> 4) << 3;
        const int fr = lane & 15;
        short8 af[MF], bfr[NF];
        if (AF32) {
            const int c0 = (lane >> 4) << 1;   // first 16B chunk of my k-slice
            #pragma unroll
            for (int im = 0; im < MF; ++im) {
                int row = wm + im * 16 + fr;
                int s   = row & 7;
                const float* ar = (const float*)&Alds[buf][row][0];
                f32x4 lo = *(const f32x4*)(ar + (((c0    ) ^ s) << 2));
                f32x4 hi = *(const f32x4*)(ar + (((c0 + 1) ^ s) << 2));
                union { short8 v; __hip_bfloat162 h[4]; } a;
                a.h[0] = __float22bfloat162_rn(make_float2(lo.x, lo.y));
                a.h[1] = __float22bfloat162_rn(make_float2(lo.z, lo.w));
                a.h[2] = __float22bfloat162_rn(make_float2(hi.x, hi.y));
                a.h[3] = __float22bfloat162_rn(make_float2(hi.z, hi.w));
                af[im] = a.v;
            }
        } else {
            #pragma unroll
            for (int im = 0; im < MF; ++im)
                af[im] = *(const short8*)(&Alds[buf][wm + im * 16 + fr][kq]);
        }
        #pragma unroll
        for (int in = 0; in < NF; ++in)
            bfr[in] = *(const short8*)(&Blds[buf][wn + in * 16 + fr][kq]);
        #pragma unroll
        for (int im = 0; im < MF; ++im)
            #pragma unroll
            for (int in = 0; in < NF; ++in)
                acc[im][in] = __builtin_amdgcn_mfma_f32_16x16x32_bf16(
                    af[im], bfr[in], acc[im][in], 0, 0, 0);
    };

    const int nt = K / BK;
    if (PIPE) {
        // 3-buffer counted-vmcnt pipeline. Invariant at top of iter t:
        // tiles t (LPT loads) and t+1 (LPT) outstanding per wave.
        // vmcnt(LPT) retires tile t (oldest-first); raw barrier then proves
        // all waves' tile-t loads landed. stage(t+2) goes AFTER the barrier
        // because buffer (t+2)%3 == (t-1)%3 was read in compute(t-1).
        stage(0, 0);
        stage(1, BK);
        for (int t = 0; t < nt; ++t) {
            if (t < nt - 1) {
                if constexpr (LPT == 4)
                    asm volatile("s_waitcnt vmcnt(4)" ::: "memory");
                else if constexpr (LPT == 3)
                    asm volatile("s_waitcnt vmcnt(3)" ::: "memory");
                else if constexpr (LPT == 2)
                    asm volatile("s_waitcnt vmcnt(2)" ::: "memory");
                else
                    asm volatile("s_waitcnt vmcnt(0)" ::: "memory");
            } else {
                asm volatile("s_waitcnt vmcnt(0)" ::: "memory");
            }
            __builtin_amdgcn_s_barrier();
            __builtin_amdgcn_sched_barrier(0);
            const int nx = t + 2;
            if (nx < nt) stage(nx - nx / 3 * 3, nx * BK);
            compute(t - t / 3 * 3);
        }
        __builtin_amdgcn_s_barrier();   // all reads done before block exits
    } else {
        for (int t = 0; t < nt; ++t) {
            __syncthreads();
            stage(0, t * BK);
            __syncthreads();
            compute(0);
        }
    }

    // ---- epilogue: C[row=(lane>>4)*4+r][col=lane&15] ----
    float* Cfp = (float*)Csel + (long long)zh * sCh + (long long)zb * sCb;
    u16*   Cbf = (u16*)Csel + (long long)zh * sCh + (long long)zb * sCb;
    const float* biasp = bsel ? bsel + (long long)zh * sbias : nullptr;
    const int rb  = (lane >> 4) << 2;
    const int col = lane & 15;
    #pragma unroll
    for (int im = 0; im < MF; ++im) {
        #pragma unroll
        for (int r = 0; r < 4; ++r) {
            int row = m0 + wm + im * 16 + rb + r;
            float rbias = (biasp && ROWBIAS) ? biasp[row] : 0.0f;
            #pragma unroll
            for (int in = 0; in < NF; ++in) {
                int cc = nC + wn + in * 16 + col;
                float v = acc[im][in][r] * scale;
                if (biasp) v += ROWBIAS ? rbias : biasp[cc];
                if (OUTF32) Cfp[(long long)row * ldc + cc] = v;
                else        Cbf[(long long)row * ldc + cc] = f2bf(v);
            }
        }
    }
}

// In-place softmax over rows of 1024 fp32. One 256-thread block per row.
__global__ __launch_bounds__(256)
void softmax_kernel(float* __restrict__ attn)
{
    const long long row = blockIdx.x;
    float* p = attn + row * 1024;
    const int tid  = threadIdx.x;
    const int lane = tid & 63;
    const int wave = tid >> 6;
    __shared__ float red[8];

    f32x4 v = *(f32x4*)(p + tid * 4);
    float mx = fmaxf(fmaxf(v.x, v.y), fmaxf(v.z, v.w));
    #pragma unroll
    for (int off = 1; off < 64; off <<= 1)
        mx = fmaxf(mx, __shfl_xor(mx, off, 64));
    if (lane == 0) red[wave] = mx;
    __syncthreads();
    mx = fmaxf(fmaxf(red[0], red[1]), fmaxf(red[2], red[3]));

    v.x = __expf(v.x - mx);
    v.y = __expf(v.y - mx);
    v.z = __expf(v.z - mx);
    v.w = __expf(v.w - mx);
    float s = v.x + v.y + v.z + v.w;
    #pragma unroll
    for (int off = 1; off < 64; off <<= 1)
        s += __shfl_xor(s, off, 64);
    if (lane == 0) red[4 + wave] = s;
    __syncthreads();
    s = red[4] + red[5] + red[6] + red[7];
    float inv = 1.0f / s;
    v.x *= inv; v.y *= inv; v.z *= inv; v.w *= inv;
    *(f32x4*)(p + tid * 4) = v;
}

// x fp32 -> bf16 elementwise
__global__ __launch_bounds__(256)
void cvt_kernel(const float* __restrict__ in, u16* __restrict__ out)
{
    long long i = (long long)blockIdx.x * 256 + threadIdx.x;
    f32x4 v = *(const f32x4*)(in + i * 4);
    u32x2 p;
    p.x = (unsigned)f2bf(v.x) | ((unsigned)f2bf(v.y) << 16);
    p.y = (unsigned)f2bf(v.z) | ((unsigned)f2bf(v.w) << 16);
    *(u32x2*)(out + i * 4) = p;
}

// transpose fp32 [R][C] -> bf16 [C][R]; 64x64 tiles, grid (C/64, R/64)
__global__ __launch_bounds__(256)
void wtrans_kernel(const float* __restrict__ in, u16* __restrict__ out, int R, int C)
{
    __shared__ __attribute__((aligned(16))) u16 t[64][72];
    const int r0 = blockIdx.y * 64, c0 = blockIdx.x * 64;
    const int tid = threadIdx.x;
    const int lr = tid >> 4;
    const int lc = (tid & 15) << 2;
    #pragma unroll
    for (int j = 0; j < 4; ++j) {
        int rr = lr + j * 16;
        f32x4 v = *(const f32x4*)(in + (long long)(r0 + rr) * C + c0 + lc);
        u32x2 p;
        p.x = (unsigned)f2bf(v.x) | ((unsigned)f2bf(v.y) << 16);
        p.y = (unsigned)f2bf(v.z) | ((unsigned)f2bf(v.w) << 16);
        *(u32x2*)(&t[rr][lc]) = p;
    }
    __syncthreads();
    const int oc = tid >> 2;
    const int rs = (tid & 3) << 4;
    union { short8 v; u16 e[8]; } a, b;
    #pragma unroll
    for (int j = 0; j < 8; ++j) a.e[j] = t[rs + j][oc];
    #pragma unroll
    for (int j = 0; j < 8; ++j) b.e[j] = t[rs + 8 + j][oc];
    u16* o = out + (long long)(c0 + oc) * R + r0 + rs;
    *(short8*)o = a.v;
    *(short8*)(o + 8) = b.v;
}

extern "C" void kernel_launch(void* const* d_in, const int* in_sizes, int n_in,
                              void* d_out, int out_size, void* d_ws, size_t ws_size,
                              hipStream_t stream)
{
    const float* x  = (const float*)d_in[0];
    const float* Wq = (const float*)d_in[1];
    const float* bq = (const float*)d_in[2];
    const float* Wk = (const float*)d_in[3];
    const float* bk = (const float*)d_in[4];
    const float* Wv = (const float*)d_in[5];
    const float* bv = (const float*)d_in[6];
    const float* Wo = (const float*)d_in[7];
    const float* bo = (const float*)d_in[8];

    const int B = 4, S = 1024, D = 512, H = 8;
    const int HD = H * D;   // 4096
    const int BS = B * S;   // 4096

    float* out  = (float*)d_out;                     // [4096, 512]
    float* attn = out + (long long)BS * D;           // [32, 1024, 1024]

    u16* xb   = (u16*)d_ws;                          // [4096,512]
    u16* WqT  = xb  + (long long)BS * D;
    u16* WkT  = WqT + (long long)HD * D;             // contiguous after WqT
    u16* WvT  = WkT + (long long)HD * D;
    u16* WoT  = WvT + (long long)HD * D;             // [512,4096]
    u16* buf1 = WoT + (long long)D * HD;             // [4096,4096]
    u16* buf2 = buf1 + (long long)BS * HD;

    dim3 blk(256);

    // 0) prep: x -> bf16, weights -> transposed bf16
    cvt_kernel<<<dim3(BS * D / 1024), blk, 0, stream>>>(x, xb);
    wtrans_kernel<<<dim3(HD / 64, D / 64), blk, 0, stream>>>(Wq, WqT, D, HD);
    wtrans_kernel<<<dim3(HD / 64, D / 64), blk, 0, stream>>>(Wk, WkT, D, HD);
    wtrans_kernel<<<dim3(HD / 64, D / 64), blk, 0, stream>>>(Wv, WvT, D, HD);
    wtrans_kernel<<<dim3(D / 64, HD / 64), blk, 0, stream>>>(Wo, WoT, HD, D);

    // 1) fused q,k = xb @ [WqT;WkT]^T -> buf1 / buf2   [128x128 tiles, 2048 blks]
    {
        dim3 g(2 * HD / 128, BS / 128, 1);
        gemm_bt<4,4,false,false,false,true,true><<<g, blk, 0, stream>>>(
            xb, D, 0, 0, WqT, D, 0, 0, buf1, HD, 0, 0, D, bq, 0, 1.0f, 1,
            HD, buf2, bk);
    }
    // 2) scores = q @ k^T / 512 per (h,b) -> fp32 attn region
    {
        dim3 g(S / 128, S / 128, H * B);
        gemm_bt<4,4,false,true,false,true,false><<<g, blk, 0, stream>>>(
            buf1, HD, D, (long long)S * HD,
            buf2, HD, D, (long long)S * HD,
            attn, S, (long long)B * S * S, (long long)S * S,
            D, nullptr, 0, 1.0f / (float)D, B,
            1 << 30, nullptr, nullptr);
    }
    // 3) row softmax in place
    softmax_kernel<<<dim3(H * B * S), blk, 0, stream>>>(attn);
    // 4) vT[hb][d][s] = Wv^T slice @ xb^T + bv  -> buf1 (q dead); row bias
    {
        dim3 g(S / 128, D / 128, H * B);
        gemm_bt<4,4,false,false,true,true,false><<<g, blk, 0, stream>>>(
            WvT, D, (long long)D * D, 0,
            xb, D, 0, (long long)S * D,
            buf1, S, (long long)B * D * S, (long long)D * S,
            D, bv, D, 1.0f, B,
            1 << 30, nullptr, nullptr);
    }
    // 5) ctx = attn @ vT^T per (h,b) -> buf2 bf16 (k dead)   [128x128 tiles]
    //    A staged raw-fp32 via gl2lds16 + XOR-swizzle, cvt_pk at frag load.
    //    Single-buffered (proven best); 1024 blocks; now 4 blocks/CU (VGPR cap).
    {
        dim3 g(D / 128, S / 128, H * B);
        gemm_bt<4,4,true,false,false,false,false><<<g, blk, 0, stream>>>(
            attn, S, (long long)B * S * S, (long long)S * S,
            buf1, S, (long long)B * D * S, (long long)D * S,
            buf2, HD, D, (long long)S * HD,
            S, nullptr, 0, 1.0f, B,
            1 << 30, nullptr, nullptr);
    }
    // 6) out = ctx @ WoT^T + bo -> fp32   [64x64 tiles, 512 blocks]
    {
        dim3 g(D / 64, BS / 64, 1);
        gemm_bt<2,2,false,true,false,true,false><<<g, blk, 0, stream>>>(
            buf2, HD, 0, 0, WoT, HD, 0, 0, out, D, 0, 0, HD, bo, 0, 1.0f, 1,
            1 << 30, nullptr, nullptr);
    }
}